// Round 21
// baseline (855.392 us; speedup 1.0000x reference)
//
#include <hip/hip_runtime.h>

// SimpleRNN: x(256,2048,8) f32, h(1,256,128), W_ih(128,8), W_hh(128,128),
// b_ih(128), b_hh(128), W_head(1,128), b_head(1)
// out = [pred(256) | last_step_features(256,128) | h_n(256,128)]  (f32)
//
// R19: no-reduce family. 256 blocks x 128 threads (2 waves). Thread owns
// output j=tid: full k=128 dot via v_dot2_f32_f16 builtin (f32 accum,
// R16-verified numerics) -> NO cross-lane reduce on the critical path,
// 2-wave barrier (vs 4), MAC issue halved.
//  - weights: 64 f16x2/lane, cvt'd from LDS-staged W_hh (ds_read is not
//    rematerializable -- R12/R15-verified residency mechanism; R15 showed
//    VGPR 132 achievable at 128 threads).
//  - W_lds row stride 132 floats: staggers banks for the row-read init.
//  - h: f16 ping-pong [2][128] (256 B each): 16 broadcast uint4 reads +
//    1 ds_write_b16/lane (<=2-way aliasing, free per m136).
//  - lgkm-only barrier (verified), direct-global x depth-2 pipeline (R10).

typedef _Float16 f16x2 __attribute__((ext_vector_type(2)));
typedef float f32x4 __attribute__((ext_vector_type(4)));
typedef float f32x2 __attribute__((ext_vector_type(2)));

#define BB 256
#define TT 2048
#define II 8
#define HH 128
#define THREADS 128
#define WROW 132          // padded W_lds row stride (floats)

#if __has_builtin(__builtin_amdgcn_fdot2)
#define FDOT2(h2, w2, acc) acc = __builtin_amdgcn_fdot2((h2), (w2), (acc), false)
#else
#define FDOT2(h2, w2, acc) \
    asm("v_dot2_f32_f16 %0, %1, %2, %0 op_sel:[0,0,0] op_sel_hi:[1,1,1]" \
        : "+v"(acc) : "v"(h2), "v"(w2))
#endif

__global__ void
__launch_bounds__(THREADS, 1)
__attribute__((amdgpu_waves_per_eu(1, 1)))
rnn_v19_kernel(const float* __restrict__ x,
               const float* __restrict__ h0,
               const float* __restrict__ W_ih,
               const float* __restrict__ W_hh,
               const float* __restrict__ b_ih,
               const float* __restrict__ b_hh,
               const float* __restrict__ W_head,
               const float* __restrict__ b_head,
               float* __restrict__ out)
{
    __shared__ __align__(16) float    W_lds[HH * WROW];  // staged W_hh (padded)
    __shared__ __align__(16) _Float16 h_lds[2][HH];      // f16 ping-pong h
    __shared__ float part[HH];

    const int b   = blockIdx.x;
    const int tid = threadIdx.x;
    const int w   = tid >> 6;
    const int l   = tid & 63;
    const int j   = tid;             // this thread's output index 0..127

    // ---- stage W_hh global -> LDS (padded rows), coalesced ----
    {
        const f32x4* Wg = (const f32x4*)W_hh;
        #pragma unroll
        for (int q = 0; q < 32; ++q) {
            const int idx = q * THREADS + tid;     // f32x4 index 0..4095
            const int e   = idx * 4;               // flat element
            const int r   = e >> 7, c = e & 127;
            *(f32x4*)&W_lds[r * WROW + c] = Wg[idx];
        }
    }
    h_lds[0][j] = (_Float16)h0[b * HH + j];
    __syncthreads();

    // ---- weights: row j from LDS, cvt to 64 f16x2 (non-remat source) ----
    f16x2 w2[64];
    {
        const float* wr = &W_lds[j * WROW];
        #pragma unroll
        for (int p = 0; p < 64; ++p) {
            f16x2 v;
            v.x = (_Float16)wr[2 * p];
            v.y = (_Float16)wr[2 * p + 1];
            w2[p] = v;
        }
    }
    float wxv[II];
    #pragma unroll
    for (int i = 0; i < II; ++i) wxv[i] = W_ih[j * II + i];
    const float bias = b_ih[j] + b_hh[j];

    // ---- x: direct global reads, depth-2 register pipeline ----
    const float* xg = x + (size_t)b * TT * II;
    f32x4 xa0 = *(const f32x4*)(xg + 0 * II), xb0 = *(const f32x4*)(xg + 0 * II + 4);
    f32x4 xa1 = *(const f32x4*)(xg + 1 * II), xb1 = *(const f32x4*)(xg + 1 * II + 4);

    float hA = 0.0f;

    #define STEP(XA, XB, RBUF, TN)                                            \
    {                                                                         \
        float a0 = bias, a1 = 0.0f, a2 = 0.0f, a3 = 0.0f;                     \
        a0 = fmaf(XA.x, wxv[0], a0);                                          \
        a1 = fmaf(XA.y, wxv[1], a1);                                          \
        a2 = fmaf(XA.z, wxv[2], a2);                                          \
        a3 = fmaf(XA.w, wxv[3], a3);                                          \
        a0 = fmaf(XB.x, wxv[4], a0);                                          \
        a1 = fmaf(XB.y, wxv[5], a1);                                          \
        a2 = fmaf(XB.z, wxv[6], a2);                                          \
        a3 = fmaf(XB.w, wxv[7], a3);                                          \
        const uint4* hp = (const uint4*)&h_lds[RBUF][0];                      \
        _Pragma("unroll")                                                     \
        for (int q = 0; q < 16; ++q) {                                        \
            const uint4 u = hp[q];                                            \
            FDOT2(__builtin_bit_cast(f16x2, u.x), w2[4 * q + 0], a0);         \
            FDOT2(__builtin_bit_cast(f16x2, u.y), w2[4 * q + 1], a1);         \
            FDOT2(__builtin_bit_cast(f16x2, u.z), w2[4 * q + 2], a2);         \
            FDOT2(__builtin_bit_cast(f16x2, u.w), w2[4 * q + 3], a3);         \
        }                                                                     \
        const float s = (a0 + a1) + (a2 + a3);                                \
        const float e2 = __builtin_amdgcn_exp2f(s * 2.8853900817779268f);     \
        hA = 1.0f - 2.0f * __builtin_amdgcn_rcpf(e2 + 1.0f);                  \
        h_lds[(RBUF) ^ 1][j] = (_Float16)hA;                                  \
        { const int tn_ = (TN) < TT ? (TN) : (TT - 1);                        \
          XA = *(const f32x4*)(xg + (size_t)tn_ * II);                        \
          XB = *(const f32x4*)(xg + (size_t)tn_ * II + 4); }                  \
        asm volatile("s_waitcnt lgkmcnt(0)\n\ts_barrier" ::: "memory");       \
    }

    for (int t = 0; t < TT; t += 2) {
        STEP(xa0, xb0, 0, t + 2)   // even step: reads buf0, writes buf1
        STEP(xa1, xb1, 1, t + 3)   // odd  step: reads buf1, writes buf0
    }
    #undef STEP

    // ---- epilogue: lane holds final f32 h for its j ----
    out[BB + (size_t)b * HH + j]           = hA;   // last_step_features
    out[BB + BB * HH + (size_t)b * HH + j] = hA;   // h_n
    part[j] = hA * W_head[j];
    __syncthreads();
    if (w == 0) {
        float s = part[l] + part[l + 64];
        #pragma unroll
        for (int off = 32; off > 0; off >>= 1) s += __shfl_down(s, off);
        if (l == 0) out[b] = s + b_head[0];
    }
}

extern "C" void kernel_launch(void* const* d_in, const int* in_sizes, int n_in,
                              void* d_out, int out_size, void* d_ws, size_t ws_size,
                              hipStream_t stream) {
    const float* x      = (const float*)d_in[0];
    const float* h0     = (const float*)d_in[1];
    const float* W_ih   = (const float*)d_in[2];
    const float* W_hh   = (const float*)d_in[3];
    const float* b_ih   = (const float*)d_in[4];
    const float* b_hh   = (const float*)d_in[5];
    const float* W_head = (const float*)d_in[6];
    const float* b_head = (const float*)d_in[7];
    float* out = (float*)d_out;

    hipLaunchKernelGGL(rnn_v19_kernel, dim3(BB), dim3(THREADS), 0, stream,
                       x, h0, W_ih, W_hh, b_ih, b_hh, W_head, b_head, out);
}